// Round 8
// baseline (2601.450 us; speedup 1.0000x reference)
//
#include <hip/hip_runtime.h>
#include <cstdint>
#include <cstddef>

#define B_ 2
#define T_ 4096
#define D_ 2048
#define H_ 8
#define DK_ 128
#define DV_ 256
#define BT_ (B_*T_)
#define NQK_ 1024
#define NV_ 2048
#define N1_ 6144   // packed: q[0,1024) k[1024,2048) v[2048,4096) gate[4096,6144)

typedef __bf16 bf16x8 __attribute__((ext_vector_type(8)));
typedef __bf16 bf16x4 __attribute__((ext_vector_type(4)));
typedef short short4_t __attribute__((ext_vector_type(4)));
typedef float f32x4 __attribute__((ext_vector_type(4)));

#define GAS __attribute__((address_space(1)))
#define LAS __attribute__((address_space(3)))

__device__ __forceinline__ float bfu(unsigned short u) {
  union { unsigned int i; float f; } c; c.i = ((unsigned int)u) << 16; return c.f;
}
__device__ __forceinline__ float bflo(unsigned int u) {
  union { unsigned int i; float f; } c; c.i = u << 16; return c.f;
}
__device__ __forceinline__ float bfhi(unsigned int u) {
  union { unsigned int i; float f; } c; c.i = u & 0xFFFF0000u; return c.f;
}
__device__ __forceinline__ unsigned short f2bf(float f) {
  union { float f; unsigned int i; } c; c.f = f;
  unsigned int x = c.i;
  x += 0x7FFFu + ((x >> 16) & 1u);
  return (unsigned short)(x >> 16);
}
__device__ __forceinline__ unsigned int pack2(float a, float b) {
  return (unsigned int)f2bf(a) | ((unsigned int)f2bf(b) << 16);
}
__device__ __forceinline__ float siluf(float x) { return x / (1.f + __expf(-x)); }
__device__ __forceinline__ float redsum32(float v) {
  #pragma unroll
  for (int m = 16; m >= 1; m >>= 1) v += __shfl_xor(v, m);
  return v;
}
__device__ __forceinline__ void async_copy16(void* lds, const void* gsrc) {
  __builtin_amdgcn_global_load_lds((const GAS unsigned int*)gsrc,
                                   (LAS unsigned int*)lds, 16, 0, 0);
}

// K=16 bf16 MFMA wrapper. B-operand lane mapping (k = 4*(l>>4)+j) matches the
// C/D row mapping ((l>>4)*4+reg), so C outputs chain into B operands directly.
__device__ __forceinline__ f32x4 mfma16(bf16x4 a, bf16x4 b, f32x4 c) {
#if __has_builtin(__builtin_amdgcn_mfma_f32_16x16x16_bf16)
  return __builtin_amdgcn_mfma_f32_16x16x16_bf16(a, b, c, 0, 0, 0);
#else
  short4_t as = __builtin_bit_cast(short4_t, a);
  short4_t bs = __builtin_bit_cast(short4_t, b);
  return __builtin_amdgcn_mfma_f32_16x16x16bf16_1k(as, bs, c, 0, 0, 0);
#endif
}
__device__ __forceinline__ bf16x4 tobf4(f32x4 v) {
  bf16x4 r;
  r[0] = (__bf16)v[0]; r[1] = (__bf16)v[1]; r[2] = (__bf16)v[2]; r[3] = (__bf16)v[3];
  return r;
}

// ---------------- cast x (f32 -> bf16) ----------------
__global__ __launch_bounds__(256) void cast_x_kernel(const float* __restrict__ in,
                                                     unsigned short* __restrict__ out) {
  size_t i = ((size_t)blockIdx.x * 256 + threadIdx.x) * 4;
  float4 v = *(const float4*)(in + i);
  uint2 r;
  r.x = pack2(v.x, v.y);
  r.y = pack2(v.z, v.w);
  *(uint2*)(out + i) = r;
}

// ---------------- transpose + cast weight (f32 [R][C] -> bf16 [C][R]) ----------------
__global__ __launch_bounds__(256) void transpose_cast(const float* __restrict__ in,
                                                      unsigned short* __restrict__ out,
                                                      int R, int Cc) {
  __shared__ float tile[32][33];
  int c0 = blockIdx.x * 32, r0 = blockIdx.y * 32;
  int tx = threadIdx.x, ty = threadIdx.y;  // (32,8)
  #pragma unroll
  for (int i = 0; i < 4; ++i)
    tile[ty + i*8][tx] = in[(size_t)(r0 + ty + i*8) * Cc + c0 + tx];
  __syncthreads();
  #pragma unroll
  for (int i = 0; i < 4; ++i)
    out[(size_t)(c0 + ty + i*8) * R + r0 + tx] = f2bf(tile[tx][ty + i*8]);
}

// ---------------- bf16 MFMA GEMM: C[M,N] = A[M,K] * Bt[N,K]^T ----------------
template<int BF16OUT>
__global__ __launch_bounds__(256) void gemm_kernel(
    const unsigned short* __restrict__ A,   // [M][K] bf16
    const unsigned short* __restrict__ Bt,  // [N][K] bf16
    void* __restrict__ Cout,
    int M, int N, int K)
{
  __shared__ __align__(16) unsigned short As[128][32];
  __shared__ __align__(16) unsigned short Bs[128][32];
  const int tid  = threadIdx.x;
  const int lane = tid & 63;
  const int wave = tid >> 6;
  const int wr = wave >> 1, wc = wave & 1;
  const int row0 = blockIdx.y * 128, col0 = blockIdx.x * 128;
  f32x4 acc[4][4];
  #pragma unroll
  for (int m = 0; m < 4; ++m)
    #pragma unroll
    for (int n = 0; n < 4; ++n)
      acc[m][n] = (f32x4){0.f, 0.f, 0.f, 0.f};

  const int fr = lane & 15;   // row within 16x16 frag
  const int fq = lane >> 4;   // k-quad (8 contiguous k per lane)

  for (int k0 = 0; k0 < K; k0 += 32) {
    #pragma unroll
    for (int i = 0; i < 2; ++i) {
      int c = tid + i * 256;          // chunk id 0..511 -> LDS byte c*16 (linear)
      int r = c >> 2, o = (c & 3) * 8;
      async_copy16(&As[r][o], A  + (size_t)(row0 + r) * K + k0 + o);
      async_copy16(&Bs[r][o], Bt + (size_t)(col0 + r) * K + k0 + o);
    }
    asm volatile("s_waitcnt vmcnt(0)" ::: "memory");
    __syncthreads();
    bf16x8 af[4], bfr[4];
    #pragma unroll
    for (int m = 0; m < 4; ++m)
      af[m] = *(const bf16x8*)&As[wr*64 + m*16 + fr][fq*8];
    #pragma unroll
    for (int n = 0; n < 4; ++n)
      bfr[n] = *(const bf16x8*)&Bs[wc*64 + n*16 + fr][fq*8];
    #pragma unroll
    for (int m = 0; m < 4; ++m)
      #pragma unroll
      for (int n = 0; n < 4; ++n)
        acc[m][n] = __builtin_amdgcn_mfma_f32_16x16x32_bf16(af[m], bfr[n], acc[m][n], 0, 0, 0);
    __syncthreads();
  }
  // C/D layout: col = lane&15, row = (lane>>4)*4 + reg
  const int fc = lane & 15, fg = lane >> 4;
  #pragma unroll
  for (int m = 0; m < 4; ++m)
    #pragma unroll
    for (int n = 0; n < 4; ++n)
      #pragma unroll
      for (int r = 0; r < 4; ++r) {
        size_t idx = (size_t)(row0 + wr*64 + m*16 + fg*4 + r) * N
                   + (col0 + wc*64 + n*16 + fc);
        if (BF16OUT) ((unsigned short*)Cout)[idx] = f2bf(acc[m][n][r]);
        else         ((float*)Cout)[idx]          = acc[m][n][r];
      }
}

// ---------------- beta / g projection (f32, N=16) ----------------
// Stores interleaved (beta, g) pairs; the chunked delta kernel needs RAW g
// for cumulative-decay sums.
__global__ __launch_bounds__(256) void beta_g_kernel(
    const float* __restrict__ x, const float* __restrict__ Wb, const float* __restrict__ Wa,
    const float* __restrict__ A_log, const float* __restrict__ dtb,
    float* __restrict__ bg)
{
  const int t = blockIdx.x;
  const int wave = threadIdx.x >> 6;
  const int lane = threadIdx.x & 63;
  const float* xr = x + (size_t)t * D_;
  float acc[4] = {0.f, 0.f, 0.f, 0.f};
  for (int k = lane; k < D_; k += 64) {
    float xv = xr[k];
    #pragma unroll
    for (int i = 0; i < 4; ++i) {
      int o = wave + 4 * i;                 // 0..7: beta heads, 8..15: a heads
      float w = (o < 8) ? Wb[(size_t)k * 8 + o] : Wa[(size_t)k * 8 + (o - 8)];
      acc[i] += xv * w;
    }
  }
  #pragma unroll
  for (int i = 0; i < 4; ++i) {
    #pragma unroll
    for (int m = 32; m >= 1; m >>= 1) acc[i] += __shfl_xor(acc[i], m);
  }
  if (lane == 0) {
    #pragma unroll
    for (int i = 0; i < 4; ++i) {
      int o = wave + 4 * i;
      if (o < 8) {
        bg[((size_t)t * H_ + o) * 2] = 1.f / (1.f + __expf(-acc[i]));
      } else {
        int h = o - 8;
        float z = acc[i] + dtb[h];
        float sp = (z > 20.f) ? z : log1pf(__expf(z));
        bg[((size_t)t * H_ + h) * 2 + 1] = -__expf(A_log[h]) * sp;
      }
    }
  }
}

// ---------------- causal dwconv(W=4) + silu + l2norm ----------------
__global__ __launch_bounds__(256) void conv_kernel(
    const unsigned short* __restrict__ Y1,
    const float* __restrict__ cq, const float* __restrict__ ck, const float* __restrict__ cv,
    float* __restrict__ qf, float* __restrict__ kf, float* __restrict__ vf)
{
  const int t  = blockIdx.x;          // global row (b*T + tt)
  const int tt = t & (T_ - 1);
  const int tid = threadIdx.x;
  const int c4 = tid * 4;
  const int c8 = tid * 8;

  float wqa[4][4], wka[4][4], wva[8][4];
  #pragma unroll
  for (int m = 0; m < 4; ++m) {
    float4 a = *(const float4*)(cq + (size_t)(c4 + m) * 4);
    wqa[m][0] = a.x; wqa[m][1] = a.y; wqa[m][2] = a.z; wqa[m][3] = a.w;
    float4 b = *(const float4*)(ck + (size_t)(c4 + m) * 4);
    wka[m][0] = b.x; wka[m][1] = b.y; wka[m][2] = b.z; wka[m][3] = b.w;
  }
  #pragma unroll
  for (int m = 0; m < 8; ++m) {
    float4 a = *(const float4*)(cv + (size_t)(c8 + m) * 4);
    wva[m][0] = a.x; wva[m][1] = a.y; wva[m][2] = a.z; wva[m][3] = a.w;
  }

  float aq[4] = {0,0,0,0}, ak[4] = {0,0,0,0}, av[8] = {0,0,0,0,0,0,0,0};
  #pragma unroll
  for (int i = 0; i < 4; ++i) {
    if (tt + i >= 3) {      // tap i reads x[t-3+i]
      const unsigned short* row = Y1 + (size_t)(t + i - 3) * N1_;
      ushort4 yq = *(const ushort4*)(row + c4);
      ushort4 yk = *(const ushort4*)(row + NQK_ + c4);
      int4    yv = *(const int4*)(row + 2 * NQK_ + c8);
      float qv[4] = { bfu(yq.x), bfu(yq.y), bfu(yq.z), bfu(yq.w) };
      float kv[4] = { bfu(yk.x), bfu(yk.y), bfu(yk.z), bfu(yk.w) };
      unsigned int vu[4] = { (unsigned)yv.x, (unsigned)yv.y, (unsigned)yv.z, (unsigned)yv.w };
      float vv[8] = { bflo(vu[0]), bfhi(vu[0]), bflo(vu[1]), bfhi(vu[1]),
                      bflo(vu[2]), bfhi(vu[2]), bflo(vu[3]), bfhi(vu[3]) };
      #pragma unroll
      for (int m = 0; m < 4; ++m) { aq[m] += qv[m] * wqa[m][i]; ak[m] += kv[m] * wka[m][i]; }
      #pragma unroll
      for (int m = 0; m < 8; ++m) av[m] += vv[m] * wva[m][i];
    }
  }
  float sq[4], sk[4], ssq = 0.f, ssk = 0.f;
  #pragma unroll
  for (int m = 0; m < 4; ++m) {
    sq[m] = siluf(aq[m]); ssq += sq[m] * sq[m];
    sk[m] = siluf(ak[m]); ssk += sk[m] * sk[m];
  }
  ssq = redsum32(ssq);   // head = tid/32; 32-lane groups align with heads
  ssk = redsum32(ssk);
  float scq = rsqrtf(ssq + 1e-6f) * 0.08838834764831845f;  // * DK^-0.5
  float sck = rsqrtf(ssk + 1e-6f);
  float4 oq = { sq[0]*scq, sq[1]*scq, sq[2]*scq, sq[3]*scq };
  float4 ok = { sk[0]*sck, sk[1]*sck, sk[2]*sck, sk[3]*sck };
  *(float4*)(qf + (size_t)t * NQK_ + c4) = oq;
  *(float4*)(kf + (size_t)t * NQK_ + c4) = ok;
  float4 ov0 = { siluf(av[0]), siluf(av[1]), siluf(av[2]), siluf(av[3]) };
  float4 ov1 = { siluf(av[4]), siluf(av[5]), siluf(av[6]), siluf(av[7]) };
  *(float4*)(vf + (size_t)t * NV_ + c8)     = ov0;
  *(float4*)(vf + (size_t)t * NV_ + c8 + 4) = ov1;
}

// ---------------- chunked gated delta-rule (MFMA) ----------------
// One wave per (b, h, 64-col DV slice): 64 workgroups. CHUNK=64.
// Identity (gs = inclusive cumsum of g within chunk; all exp ratios <= 1):
//   (I - M) u = beta (.) (V - exp(gs) (.) (K S0)),
//      M[t,s] = -beta_t e^{gs_t-gs_s} (k_t.k_s), strict lower (minus baked in)
//   O = exp(gs) (.) (Q S0) + (QK^T (.) decay, s<=t) U
//   S' = e^{gs_C} S0 + K'^T U,  K'_s = e^{gs_C-gs_s} k_s
// Layout plan: 16x16x16 bf16 MFMA only. B-operand (k=4*(l>>4)+j) == C-row
// mapping -> u/rhs/S chain C->B for free; M/QK/T go C->A via padded LDS.
// S kept f32 (MFMA C accumulate), cast to bf16 once per chunk.
__global__ __launch_bounds__(64, 1) void delta_kernel(
    const float* __restrict__ qf, const float* __restrict__ kf,
    const float* __restrict__ vf, const float* __restrict__ bg,
    float* __restrict__ o)
{
  __shared__ float sc_beta[64], sc_gs[64], sc_eg[64], sc_esC[64];
  __shared__ unsigned short Mlds[64 * 68];    // [t][s] pad 68 -> conflict-free b64 reads
  __shared__ unsigned short QKlds[64 * 68];
  __shared__ unsigned short Tlds[64 * 20];    // 4 blocks x [16][20]

  const int blk = blockIdx.x;
  const int bh = blk & 15;              // same bh -> same XCD (L2 shares Q/K)
  const int slice = blk >> 4;           // 0..3 DV slice
  const int b = bh >> 3, h = bh & 7;
  const int lane = threadIdx.x;
  const int r16 = lane & 15;
  const int g4 = lane >> 4;
  const int dv0 = slice * 64;
  const size_t bT = (size_t)b * T_;

  f32x4 S[8][4];
  #pragma unroll
  for (int i = 0; i < 8; ++i)
    #pragma unroll
    for (int j = 0; j < 4; ++j) S[i][j] = (f32x4){0.f, 0.f, 0.f, 0.f};

  for (int c = 0; c < T_ / 64; ++c) {
    const int t0 = c * 64;

    // ---- scalars: (beta, g) load, 64-lane inclusive scan of g ----
    float2 bgl = *(const float2*)(bg + ((bT + t0 + lane) * H_ + h) * 2);
    float gs = bgl.y;
    #pragma unroll
    for (int d = 1; d < 64; d <<= 1) {
      float nb = __shfl_up(gs, d);
      if (lane >= d) gs += nb;
    }
    float gsC = __shfl(gs, 63);
    sc_beta[lane] = bgl.x;
    sc_gs[lane]   = gs;
    sc_eg[lane]   = __expf(gs);
    sc_esC[lane]  = __expf(gsC - gs);
    float egC = __expf(gsC);
    __syncthreads();

    // ---- load Q, K as K16 A-frags: row = r16, k = kb*16 + 4*g4 + j ----
    bf16x4 Qf[4][8], Kf[4][8];
    #pragma unroll
    for (int tt = 0; tt < 4; ++tt) {
      const float* qrow = qf + (bT + t0 + tt*16 + r16) * NQK_ + h*DK_ + g4*4;
      const float* krow = kf + (bT + t0 + tt*16 + r16) * NQK_ + h*DK_ + g4*4;
      #pragma unroll
      for (int kb = 0; kb < 8; ++kb) {
        float4 qv = *(const float4*)(qrow + kb*16);
        float4 kv = *(const float4*)(krow + kb*16);
        Qf[tt][kb] = (bf16x4){(__bf16)qv.x, (__bf16)qv.y, (__bf16)qv.z, (__bf16)qv.w};
        Kf[tt][kb] = (bf16x4){(__bf16)kv.x, (__bf16)kv.y, (__bf16)kv.z, (__bf16)kv.w};
      }
    }

    // ---- KK^T & QK^T (lower tiles), mask+scale, write bf16 to LDS ----
    #pragma unroll
    for (int tt = 0; tt < 4; ++tt) {
      #pragma unroll
      for (int ts = 0; ts < 4; ++ts) {
        if (ts > tt) continue;
        f32x4 ck = (f32x4){0,0,0,0}, cq = (f32x4){0,0,0,0};
        #pragma unroll
        for (int kb = 0; kb < 8; ++kb) {
          ck = mfma16(Kf[tt][kb], Kf[ts][kb], ck);   // A rows t, B cols s (same frag)
          cq = mfma16(Qf[tt][kb], Kf[ts][kb], cq);
        }
        #pragma unroll
        for (int rg = 0; rg < 4; ++rg) {
          int tl = tt*16 + g4*4 + rg;
          int s  = ts*16 + r16;
          float dec = __expf(sc_gs[tl] - sc_gs[s]);
          float mval = (tl > s)  ? -sc_beta[tl] * dec * ck[rg] : 0.f;
          float qval = (tl >= s) ? dec * cq[rg] : 0.f;
          Mlds[tl*68 + s]  = f2bf(mval);
          QKlds[tl*68 + s] = f2bf(qval);
        }
      }
    }
    __syncthreads();

    // ---- Sb = bf16(S) (B-frags, free from C layout) ----
    bf16x4 Sb[8][4];
    #pragma unroll
    for (int i = 0; i < 8; ++i)
      #pragma unroll
      for (int j = 0; j < 4; ++j) Sb[i][j] = tobf4(S[i][j]);

    // ---- rhs = beta (.) (V - eg (.) (K S0))  [C layout f32] ----
    f32x4 rhs[4][4];
    #pragma unroll
    for (int tt = 0; tt < 4; ++tt)
      #pragma unroll
      for (int td = 0; td < 4; ++td) {
        f32x4 a = (f32x4){0,0,0,0};
        #pragma unroll
        for (int kb = 0; kb < 8; ++kb) a = mfma16(Kf[tt][kb], Sb[kb][td], a);
        f32x4 rr;
        #pragma unroll
        for (int rg = 0; rg < 4; ++rg) {
          int tl = tt*16 + g4*4 + rg;
          float v = vf[(bT + t0 + tl) * NV_ + h*DV_ + dv0 + td*16 + r16];
          rr[rg] = sc_beta[tl] * fmaf(-sc_eg[tl], a[rg], v);
        }
        rhs[tt][td] = rr;
      }

    // ---- O = eg (.) (Q S0)  [C layout f32] ----
    f32x4 O[4][4];
    #pragma unroll
    for (int tt = 0; tt < 4; ++tt)
      #pragma unroll
      for (int td = 0; td < 4; ++td) {
        f32x4 a = (f32x4){0,0,0,0};
        #pragma unroll
        for (int kb = 0; kb < 8; ++kb) a = mfma16(Qf[tt][kb], Sb[kb][td], a);
        #pragma unroll
        for (int rg = 0; rg < 4; ++rg) a[rg] *= sc_eg[tt*16 + g4*4 + rg];
        O[tt][td] = a;
      }

    // ---- T_ii = (I - M_ii)^{-1}: group g4 inverts block g4 (col r16) ----
    {
      float tc[16];
      #pragma unroll
      for (int t = 0; t < 16; ++t) {
        float acc = (r16 == t) ? 1.f : 0.f;
        #pragma unroll
        for (int s = 0; s < 16; ++s) {
          if (s < t) {
            float m = bfu(Mlds[(g4*16 + t)*68 + g4*16 + s]);  // minus baked in
            acc = fmaf(m, tc[s], acc);
          }
        }
        tc[t] = acc;
        Tlds[(g4*16 + t)*20 + r16] = f2bf(acc);
      }
    }
    __syncthreads();

    // ---- blocked solve: u_i = T_ii (rhs_i + sum_{j<i} M_ij u_j) ----
    bf16x4 ub[4][4];
    #pragma unroll
    for (int i = 0; i < 4; ++i) {
      f32x4 w[4];
      #pragma unroll
      for (int td = 0; td < 4; ++td) w[td] = rhs[i][td];
      #pragma unroll
      for (int j = 0; j < 4; ++j) {
        if (j < i) {
          uint2 mr = *(const uint2*)&Mlds[(i*16 + r16)*68 + j*16 + 4*g4];
          bf16x4 Mf = __builtin_bit_cast(bf16x4, mr);
          #pragma unroll
          for (int td = 0; td < 4; ++td) w[td] = mfma16(Mf, ub[j][td], w[td]);
        }
      }
      uint2 tr = *(const uint2*)&Tlds[(i*16 + r16)*20 + 4*g4];
      bf16x4 Tf = __builtin_bit_cast(bf16x4, tr);
      #pragma unroll
      for (int td = 0; td < 4; ++td) {
        f32x4 u = mfma16(Tf, tobf4(w[td]), (f32x4){0,0,0,0});
        ub[i][td] = tobf4(u);
      }
    }

    // ---- O += (QK masked) U ; store O ----
    #pragma unroll
    for (int tt = 0; tt < 4; ++tt)
      #pragma unroll
      for (int td = 0; td < 4; ++td) {
        f32x4 acc = O[tt][td];
        #pragma unroll
        for (int sb = 0; sb < 4; ++sb) {
          if (sb <= tt) {
            uint2 qr = *(const uint2*)&QKlds[(tt*16 + r16)*68 + sb*16 + 4*g4];
            acc = mfma16(__builtin_bit_cast(bf16x4, qr), ub[sb][td], acc);
          }
        }
        #pragma unroll
        for (int rg = 0; rg < 4; ++rg) {
          int tl = tt*16 + g4*4 + rg;
          o[(bT + t0 + tl) * NV_ + h*DV_ + dv0 + td*16 + r16] = acc[rg];
        }
      }

    // ---- S = egC * S + K'^T U ----
    #pragma unroll
    for (int dk8 = 0; dk8 < 8; ++dk8) {
      bf16x4 KT[4];
      #pragma unroll
      for (int sb = 0; sb < 4; ++sb) {
        bf16x4 f;
        #pragma unroll
        for (int rg = 0; rg < 4; ++rg) {
          int s = sb*16 + g4*4 + rg;
          float kv = kf[(bT + t0 + s) * NQK_ + h*DK_ + dk8*16 + r16];
          f[rg] = (__bf16)(kv * sc_esC[s]);
        }
        KT[sb] = f;
      }
      #pragma unroll
      for (int td = 0; td < 4; ++td) {
        f32x4 s4 = S[dk8][td];
        #pragma unroll
        for (int e = 0; e < 4; ++e) s4[e] *= egC;
        #pragma unroll
        for (int sb = 0; sb < 4; ++sb) s4 = mfma16(KT[sb], ub[sb][td], s4);
        S[dk8][td] = s4;
      }
    }
    __syncthreads();
  }
}

// ---------------- gated RMSNorm + silu(gate) -> bf16 ----------------
__global__ __launch_bounds__(256) void post_kernel(
    const float* __restrict__ o, const unsigned short* __restrict__ Y1,
    const float* __restrict__ gw, unsigned short* __restrict__ og)
{
  const int t = blockIdx.x;
  const int tid = threadIdx.x;
  const int e = tid * 8;       // head = tid/32, dv = e&255
  float4 v0 = *(const float4*)(o + (size_t)t * NV_ + e);
  float4 v1 = *(const float4*)(o + (size_t)t * NV_ + e + 4);
  float v[8] = { v0.x, v0.y, v0.z, v0.w, v1.x, v1.y, v1.z, v1.w };
  float ss = 0.f;
  #pragma unroll
  for (int m = 0; m < 8; ++m) ss += v[m] * v[m];
  ss = redsum32(ss);
  float rms = rsqrtf(ss * (1.f / 256.f) + 1e-5f);
  int4 graw = *(const int4*)(Y1 + (size_t)t * N1_ + 4096 + e);
  unsigned int gu[4] = { (unsigned)graw.x, (unsigned)graw.y, (unsigned)graw.z, (unsigned)graw.w };
  float gv[8] = { bflo(gu[0]), bfhi(gu[0]), bflo(gu[1]), bfhi(gu[1]),
                  bflo(gu[2]), bfhi(gu[2]), bflo(gu[3]), bfhi(gu[3]) };
  const int dv = e & 255;
  float res[8];
  #pragma unroll
  for (int m = 0; m < 8; ++m) res[m] = v[m] * rms * gw[dv + m] * siluf(gv[m]);
  int4 outv;
  outv.x = (int)pack2(res[0], res[1]);
  outv.y = (int)pack2(res[2], res[3]);
  outv.z = (int)pack2(res[4], res[5]);
  outv.w = (int)pack2(res[6], res[7]);
  *(int4*)(og + (size_t)t * NV_ + e) = outv;
}

extern "C" void kernel_launch(void* const* d_in, const int* in_sizes, int n_in,
                              void* d_out, int out_size, void* d_ws, size_t ws_size,
                              hipStream_t stream)
{
  (void)in_sizes; (void)n_in; (void)out_size;
  const float* x     = (const float*)d_in[0];
  const float* Wq    = (const float*)d_in[1];
  const float* Wk    = (const float*)d_in[2];
  const float* Wv    = (const float*)d_in[3];
  const float* Wb    = (const float*)d_in[4];
  const float* Wa    = (const float*)d_in[5];
  const float* Wg    = (const float*)d_in[6];
  const float* Wo    = (const float*)d_in[7];
  const float* cq    = (const float*)d_in[8];
  const float* ck    = (const float*)d_in[9];
  const float* cv    = (const float*)d_in[10];
  const float* A_log = (const float*)d_in[11];
  const float* dtb   = (const float*)d_in[12];
  const float* gw    = (const float*)d_in[13];

  // ---- workspace layout with lifetime-based aliasing (peak ~232.5 MiB) ----
  char* ws = (char*)d_ws;
  const size_t SZ_XB  = (size_t)BT_ * D_ * 2;       // 32 MiB
  const size_t SZ_WCT = (size_t)N1_ * D_ * 2;       // 24 MiB
  const size_t SZ_QF  = (size_t)BT_ * NQK_ * 4;     // 32 MiB
  const size_t SZ_KF  = (size_t)BT_ * NQK_ * 4;     // 32 MiB
  const size_t SZ_VF  = (size_t)BT_ * NV_ * 4;      // 64 MiB
  const size_t SZ_R1a = SZ_XB + SZ_WCT;
  const size_t SZ_R1b = SZ_QF + SZ_KF + SZ_VF;
  const size_t SZ_R1  = (SZ_R1a > SZ_R1b) ? SZ_R1a : SZ_R1b;
  const size_t SZ_WOT = (size_t)D_ * D_ * 2;        // 8 MiB
  const size_t SZ_BG  = (size_t)BT_ * H_ * 8;       // 512 KiB (float2)
  const size_t SZ_Y1  = (size_t)BT_ * N1_ * 2;      // 96 MiB

  const size_t OFF_WOT = SZ_R1;
  const size_t OFF_BG  = OFF_WOT + SZ_WOT;
  const size_t OFF_Y1  = OFF_BG + SZ_BG;
  const size_t WS_NEEDED = OFF_Y1 + SZ_Y1;
  if (ws_size < WS_NEEDED) return;

  unsigned short* xb  = (unsigned short*)(ws);                 // phase A
  unsigned short* Wct = (unsigned short*)(ws + SZ_XB);         // phase A
  float* qf = (float*)(ws);                                    // phase B
  float* kf = (float*)(ws + SZ_QF);                            // phase B
  float* vf = (float*)(ws + SZ_QF + SZ_KF);                    // phase B/C (ov aliases)
  float* ov = vf;   // chunked delta reads V(chunk) before writing O(chunk); cols disjoint per wg
  unsigned short* og  = (unsigned short*)(ws);                 // phase C
  unsigned short* Wot = (unsigned short*)(ws + OFF_WOT);
  float* bg   = (float*)(ws + OFF_BG);
  unsigned short* Y1  = (unsigned short*)(ws + OFF_Y1);

  cast_x_kernel<<<(BT_ * D_) / 1024, 256, 0, stream>>>(x, xb);
  dim3 tb(32, 8);
  transpose_cast<<<dim3(1024/32, 2048/32), tb, 0, stream>>>(Wq, Wct, 2048, 1024);
  transpose_cast<<<dim3(1024/32, 2048/32), tb, 0, stream>>>(Wk, Wct + (size_t)1024 * 2048, 2048, 1024);
  transpose_cast<<<dim3(2048/32, 2048/32), tb, 0, stream>>>(Wv, Wct + (size_t)2048 * 2048, 2048, 2048);
  transpose_cast<<<dim3(2048/32, 2048/32), tb, 0, stream>>>(Wg, Wct + (size_t)4096 * 2048, 2048, 2048);
  transpose_cast<<<dim3(2048/32, 2048/32), tb, 0, stream>>>(Wo, Wot, 2048, 2048);

  gemm_kernel<1><<<dim3(N1_/128, BT_/128), 256, 0, stream>>>(xb, Wct, Y1, BT_, N1_, D_);
  beta_g_kernel<<<BT_, 256, 0, stream>>>(x, Wb, Wa, A_log, dtb, bg);
  conv_kernel<<<BT_, 256, 0, stream>>>(Y1, cq, ck, cv, qf, kf, vf);
  delta_kernel<<<B_ * H_ * 4, 64, 0, stream>>>(qf, kf, vf, bg, ov);
  post_kernel<<<BT_, 256, 0, stream>>>(ov, Y1, gw, og);
  gemm_kernel<0><<<dim3(D_/128, BT_/128), 256, 0, stream>>>(og, Wot, d_out, BT_, D_, D_);
}